// Round 13
// baseline (214.769 us; speedup 1.0000x reference)
//
#include <hip/hip_runtime.h>

// RGCN link predictor, aggregate-first with MFMA-based mean aggregation and
// software-pipelined (double-buffered) gather staging:
//   out[i] = sum_r W_r @ mean_{j in N_r(i)} x_j + root@x_i + b
// Per (64-dst block): flat chunk table over all rels; per iteration:
//   issue gathers for chunk c+1 (regs) | MFMA-consume chunk c from buf |
//   LDS-write chunk c+1 into buf^1 (vmcnt hidden under consume) | barrier.
// Rel-boundary flush: aggD -> bf16 A-tile -> acc += A_r @ W_r (verified
// path). Root + bias (+ReLU) epilogue with direct permuted bf16 store.
//
// Output layout: true-col pi(q)=(q%CT)*16+q/CT at short-position q. hmid
// inherits pi64 (W2/root2 k-rows pre-permuted), z inherits pi32 (decode dot
// invariant), bias folded in epilogue.
//
// Problem sizes fixed by harness: N=100000, E=1e6 uniform, NREL=8.
#define F_IN 64
#define F_HID 64
#define F_OUT 32
#define NREL 8
#define SCAP 6144    // staging/rec capacity per 512-bucket (edges)
#define MAXBUCK 200
#define PA_PE 16     // edges per thread in binA
#define CTAB 96      // max chunks per 64-dst block (avg ~28)

typedef __attribute__((ext_vector_type(8))) short bfrag;   // 8 bf16 (A/B frag)
typedef __attribute__((ext_vector_type(4))) float ffrag;   // 4 f32  (C/D frag)

// ---------------------------------------------------------------------------
// bf16 helpers (manual RNE pack)
__device__ inline unsigned short f2bf(float f) {
  unsigned u = __float_as_uint(f);
  unsigned r = (u + 0x7fffu + ((u >> 16) & 1u)) >> 16;
  return (unsigned short)r;
}
__device__ inline unsigned bf16pair(float lo, float hi) {
  return (unsigned)f2bf(lo) | ((unsigned)f2bf(hi) << 16);
}
__device__ inline float bflo(unsigned u) { return __uint_as_float(u << 16); }
__device__ inline float bfhi(unsigned u) { return __uint_as_float(u & 0xffff0000u); }
__device__ inline float dot8(uint4 a, uint4 b) {
  return bflo(a.x) * bflo(b.x) + bfhi(a.x) * bfhi(b.x) +
         bflo(a.y) * bflo(b.y) + bfhi(a.y) * bfhi(b.y) +
         bflo(a.z) * bflo(b.z) + bfhi(a.z) * bfhi(b.z) +
         bflo(a.w) * bflo(b.w) + bfhi(a.w) * bfhi(b.w);
}

// ---------------------------------------------------------------------------
// Fused prep: weight fragment swizzle for both layers (+root slots) + gcur.
template <int O, bool PERMK>
__device__ inline void wprep_one(int t, const float* __restrict__ W,
                                 const float* __restrict__ root,
                                 unsigned short* __restrict__ Wf) {
  constexpr int CT = O / 16;
  int l = t & 63;
  int s = (t >> 6) & 1;
  int rc = t >> 7;
  int c = rc % CT;
  int r = rc / CT;
  const float* wsrc = (r < NREL) ? W + (size_t)r * 64 * O : root;
  unsigned short* dst = Wf + (size_t)t * 8;
  int col = c * 16 + (l & 15);
  int k0 = s * 32 + ((l >> 4) * 8);
#pragma unroll
  for (int j = 0; j < 8; ++j) {
    int k = k0 + j;
    if (PERMK) k = (k & 3) * 16 + (k >> 2);   // pi64
    dst[j] = f2bf(wsrc[(size_t)k * O + col]);
  }
}

__global__ __launch_bounds__(256) void prep_kernel(
    const float* __restrict__ W1, const float* __restrict__ root1,
    const float* __restrict__ W2, const float* __restrict__ root2,
    unsigned short* __restrict__ wf1, unsigned short* __restrict__ wf2,
    int* __restrict__ gcur, int nbuck) {
  int gid = blockIdx.x * 256 + threadIdx.x;
  const int J1 = (NREL + 1) * (F_HID / 16) * 2 * 64;  // 4608
  const int J2 = (NREL + 1) * (F_OUT / 16) * 2 * 64;  // 2304
  if (gid < J1) {
    wprep_one<F_HID, false>(gid, W1, root1, wf1);
  } else if (gid < J1 + J2) {
    wprep_one<F_OUT, true>(gid - J1, W2, root2, wf2);
  } else if (gid - J1 - J2 < nbuck) {
    int b = gid - J1 - J2;
    gcur[b] = b * SCAP;
  }
}

// f32 -> bf16 conversion, 8 elements/thread
__global__ __launch_bounds__(256) void cvt_bf16_kernel(
    const float* __restrict__ in, unsigned* __restrict__ out, int n8) {
  int i = blockIdx.x * blockDim.x + threadIdx.x;
  if (i >= n8) return;
  const float4* p = (const float4*)(in + (size_t)i * 8);
  float4 a = p[0], b = p[1];
  uint4 o;
  o.x = bf16pair(a.x, a.y);
  o.y = bf16pair(a.z, a.w);
  o.z = bf16pair(b.x, b.y);
  o.w = bf16pair(b.z, b.w);
  *((uint4*)out + i) = o;
}

// ---------------------------------------------------------------------------
// Pass A: bin edges by 512-dst bucket into per-bucket staging regions.
__global__ __launch_bounds__(256) void binA_kernel(
    const int* __restrict__ src, const int* __restrict__ dst,
    const int* __restrict__ et, int* __restrict__ gcur,
    unsigned* __restrict__ staging, int E) {
  __shared__ int hist[MAXBUCK * 4];
  __shared__ int wbase[MAXBUCK * 4];
  const int tid = threadIdx.x;
  const int wave = tid >> 6;
  for (int i = tid; i < MAXBUCK * 4; i += 256) hist[i] = 0;
  __syncthreads();
  const int base = blockIdx.x * (256 * PA_PE);
  int dv[PA_PE], rk[PA_PE];
#pragma unroll
  for (int j = 0; j < PA_PE; ++j) {
    int e = base + j * 256 + tid;
    if (e < E) {
      int d = dst[e];
      dv[j] = d;
      rk[j] = atomicAdd(&hist[(d >> 9) * 4 + wave], 1);
    } else {
      dv[j] = -1;
    }
  }
  __syncthreads();
  for (int b = tid; b < MAXBUCK; b += 256) {
    int h0 = hist[b * 4 + 0], h1 = hist[b * 4 + 1];
    int h2 = hist[b * 4 + 2], h3 = hist[b * 4 + 3];
    int tot = h0 + h1 + h2 + h3;
    int gb = tot ? atomicAdd(&gcur[b], tot) : 0;
    wbase[b * 4 + 0] = gb;
    wbase[b * 4 + 1] = gb + h0;
    wbase[b * 4 + 2] = gb + h0 + h1;
    wbase[b * 4 + 3] = gb + h0 + h1 + h2;
  }
  __syncthreads();
#pragma unroll
  for (int j = 0; j < PA_PE; ++j) {
    if (dv[j] >= 0) {
      int e = base + j * 256 + tid;
      unsigned pk = (unsigned)src[e] | ((unsigned)et[e] << 17) |
                    ((unsigned)(dv[j] & 511) << 20);
      staging[wbase[(dv[j] >> 9) * 4 + wave] + rk[j]] = pk;
    }
  }
}

// Pass B: one block per 512-bucket. Histogram the 4096 (sb,rel,dl6) lists,
// block-scan -> exact absolute starts, place 4B records {src | dl6<<17}.
__global__ __launch_bounds__(256) void binB_kernel(
    const unsigned* __restrict__ staging, const int* __restrict__ gcur,
    int* __restrict__ recI, int* __restrict__ startsD) {
  __shared__ int cnt[4096];
  __shared__ int cur[4096];
  __shared__ int tsum[256];
  const int b = blockIdx.x;
  const int tid = threadIdx.x;
  const int cnt_b = gcur[b] - b * SCAP;
  const unsigned* st = staging + (size_t)b * SCAP;
  for (int i = tid; i < 4096; i += 256) cnt[i] = 0;
  __syncthreads();
  for (int i = tid; i < cnt_b; i += 256) {
    unsigned e = st[i];
    int dl = (e >> 20) & 511;
    int idx = ((dl >> 6) << 9) | (((e >> 17) & 7) << 6) | (dl & 63);
    atomicAdd(&cnt[idx], 1);
  }
  __syncthreads();
  int loc[16];
  int tot = 0;
#pragma unroll
  for (int j = 0; j < 16; ++j) { loc[j] = cnt[tid * 16 + j]; tot += loc[j]; }
  tsum[tid] = tot;
  __syncthreads();
  for (int off = 1; off < 256; off <<= 1) {
    int v = (tid >= off) ? tsum[tid - off] : 0;
    __syncthreads();
    tsum[tid] += v;
    __syncthreads();
  }
  int run = b * SCAP + tsum[tid] - tot;
#pragma unroll
  for (int j = 0; j < 16; ++j) {
    startsD[b * 4097 + tid * 16 + j] = run;
    cur[tid * 16 + j] = run;
    run += loc[j];
  }
  if (tid == 0) startsD[b * 4097 + 4096] = gcur[b];
  __syncthreads();
  for (int i = tid; i < cnt_b; i += 256) {
    unsigned e = st[i];
    int dl = (e >> 20) & 511;
    int idx = ((dl >> 6) << 9) | (((e >> 17) & 7) << 6) | (dl & 63);
    int pos = atomicAdd(&cur[idx], 1);
    recI[pos] = (int)(e & 0x1FFFF) | ((dl & 63) << 17);
  }
}

// ---------------------------------------------------------------------------
// Pipelined aggregate-first fused layer. Block = 64 dst nodes, 256 threads.
template <int O, bool RELU>
__global__ __launch_bounds__(256) void ragg_kernel(
    const unsigned short* __restrict__ X,   // input table [.][64] bf16
    const unsigned short* __restrict__ Wf,  // 9 fragment slots
    const int* __restrict__ startsD, const int* __restrict__ recI,
    const float* __restrict__ bias, unsigned short* __restrict__ Y, int N) {
  constexpr int CT = O / 16;
  __shared__ __align__(16) unsigned short S[2][64 * 40];   // A-op: S[dl][edge]
  __shared__ __align__(16) unsigned short Xg[2][32 * 72];  // B-op: Xg[edge][feat]
  __shared__ __align__(16) unsigned short A[64 * 72];      // mean tile
  __shared__ float pinvL[512];
  __shared__ int ctabP[CTAB];
  __shared__ unsigned char ctabR[CTAB];
  __shared__ int ntotS;
  const int tid = threadIdx.x;
  const int w = tid >> 6, l = tid & 63;
  const int blk = blockIdx.x;
  const int b = blk >> 3, sb = blk & 7;
  const int ec = tid >> 3;    // edge slot 0..31
  const int ch = tid & 7;     // feature chunk (8 bf16)
  const int cl = l & 15, kgb = (l >> 4) << 3;
  const int base0 = b * 4097 + (sb << 9);

  // one-time zero (stale Xg under S=0 columns must stay finite)
  for (int i = tid; i < 2 * 64 * 40 / 2; i += 256) ((unsigned*)S)[i] = 0u;
  for (int i = tid; i < 2 * 32 * 72 / 2; i += 256) ((unsigned*)Xg)[i] = 0u;
  // pinv for all 512 (rel, dl) lists
  for (int i = tid; i < 512; i += 256) {
    int len = startsD[base0 + i + 1] - startsD[base0 + i];
    pinvL[i] = (len > 0) ? 1.0f / (float)len : 0.0f;
  }
  if (tid == 0) {   // flat chunk table over all rels (empty rels skipped)
    int nt = 0;
    for (int r = 0; r < NREL; ++r) {
      int s = startsD[base0 + (r << 6)];
      int e = startsD[base0 + (r << 6) + 64];
      for (int p = s; p < e && nt < CTAB; p += 32) {
        ctabP[nt] = p;
        ctabR[nt] = (unsigned char)r;
        ++nt;
      }
    }
    ntotS = nt;
  }
  __syncthreads();
  const int ntot = ntotS;

  ffrag acc[CT];
#pragma unroll
  for (int c = 0; c < CT; ++c) acc[c] = (ffrag){0.f, 0.f, 0.f, 0.f};
  ffrag aggD[4];
#pragma unroll
  for (int mt = 0; mt < 4; ++mt) aggD[mt] = (ffrag){0.f, 0.f, 0.f, 0.f};
  int prevdl[2] = {-1, -1};

  // ---- prologue: stage chunk 0 into buf 0 ----
  if (ntot > 0) {
    int r0 = ctabR[0];
    int pend = startsD[base0 + (r0 << 6) + 64];
    int p = ctabP[0] + ec;
    int dl = -1;
    uint4 g;
    if (p < pend) {
      int rc = recI[p];
      dl = (rc >> 17) & 63;
      g = *(const uint4*)(X + (size_t)(rc & 0x1FFFF) * 64 + ch * 8);
    }
    if (dl >= 0) *(uint4*)&Xg[0][ec * 72 + ch * 8] = g;
    if (ch == 0) {
      if (dl >= 0) S[0][dl * 40 + ec] = f2bf(pinvL[(r0 << 6) + dl]);
      prevdl[0] = dl;
    }
  }
  __syncthreads();

  int buf = 0;
  for (int c = 0; c < ntot; ++c) {
    const int r = ctabR[c];
    // (a) issue gathers for chunk c+1 (registers only)
    const bool have1 = (c + 1 < ntot);
    int dl1 = -1;
    float pv1 = 0.f;
    uint4 g1;
    if (have1) {
      int r1 = ctabR[c + 1];
      int pend = startsD[base0 + (r1 << 6) + 64];
      int p = ctabP[c + 1] + ec;
      if (p < pend) {
        int rc = recI[p];
        dl1 = (rc >> 17) & 63;
        g1 = *(const uint4*)(X + (size_t)(rc & 0x1FFFF) * 64 + ch * 8);
        if (ch == 0) pv1 = pinvL[(r1 << 6) + dl1];
      }
    }
    // (b) consume chunk c from buf
    {
      const unsigned short* xgb = Xg[buf];
      const unsigned short* sbf = S[buf];
      bfrag xf;
#pragma unroll
      for (int j = 0; j < 8; ++j) xf[j] = (short)xgb[(kgb + j) * 72 + (w << 4) + cl];
#pragma unroll
      for (int mt = 0; mt < 4; ++mt) {
        bfrag sf = *(const bfrag*)&sbf[((mt << 4) + cl) * 40 + kgb];
        aggD[mt] = __builtin_amdgcn_mfma_f32_16x16x32_bf16(sf, xf, aggD[mt], 0, 0, 0);
      }
    }
    // (c) write chunk c+1 into buf^1 (vmcnt wait hides under (b))
    if (have1) {
      const int nb = buf ^ 1;
      if (dl1 >= 0) *(uint4*)&Xg[nb][ec * 72 + ch * 8] = g1;
      if (ch == 0) {
        int pd = prevdl[nb];
        if (pd >= 0 && pd != dl1) S[nb][pd * 40 + ec] = 0;
        if (dl1 >= 0) S[nb][dl1 * 40 + ec] = f2bf(pv1);
        prevdl[nb] = dl1;
      }
    }
    const bool fl = !have1 || ((int)ctabR[c + 1] != r);
    __syncthreads();   // stage(c+1) visible; protects A-write vs prior A-reads
    // (d) rel-boundary flush: aggD -> A -> acc += A @ W_r
    if (fl) {
#pragma unroll
      for (int mt = 0; mt < 4; ++mt)
#pragma unroll
        for (int i = 0; i < 4; ++i)
          A[((mt << 4) + ((l >> 4) << 2) + i) * 72 + (w << 4) + cl] =
              f2bf(aggD[mt][i]);
#pragma unroll
      for (int mt = 0; mt < 4; ++mt) aggD[mt] = (ffrag){0.f, 0.f, 0.f, 0.f};
      __syncthreads();
      bfrag a0 = *(const bfrag*)&A[((w << 4) + cl) * 72 + kgb];
      bfrag a1 = *(const bfrag*)&A[((w << 4) + cl) * 72 + 32 + kgb];
      const unsigned short* wb = Wf + ((size_t)r * CT * 2 * 64 + l) * 8;
#pragma unroll
      for (int cc = 0; cc < CT; ++cc) {
        bfrag b0 = *(const bfrag*)(wb + (size_t)(cc * 2 + 0) * 512);
        bfrag b1 = *(const bfrag*)(wb + (size_t)(cc * 2 + 1) * 512);
        acc[cc] = __builtin_amdgcn_mfma_f32_16x16x32_bf16(a0, b0, acc[cc], 0, 0, 0);
        acc[cc] = __builtin_amdgcn_mfma_f32_16x16x32_bf16(a1, b1, acc[cc], 0, 0, 0);
      }
    }
    buf ^= 1;
  }

  // root term (slot 8): operand = own row of X
  int arow = blk * 64 + (w << 4) + cl;
  if (arow >= N) arow = N - 1;
  const unsigned short* xp = X + (size_t)arow * 64 + kgb;
  bfrag a0 = *(const bfrag*)(xp);
  bfrag a1 = *(const bfrag*)(xp + 32);
  const unsigned short* wb = Wf + ((size_t)NREL * CT * 2 * 64 + l) * 8;
#pragma unroll
  for (int cc = 0; cc < CT; ++cc) {
    bfrag b0 = *(const bfrag*)(wb + (size_t)(cc * 2 + 0) * 512);
    bfrag b1 = *(const bfrag*)(wb + (size_t)(cc * 2 + 1) * 512);
    acc[cc] = __builtin_amdgcn_mfma_f32_16x16x32_bf16(a0, b0, acc[cc], 0, 0, 0);
    acc[cc] = __builtin_amdgcn_mfma_f32_16x16x32_bf16(a1, b1, acc[cc], 0, 0, 0);
  }
  // epilogue: bias (true col = c*16 + cl), ReLU, permuted bf16 store
  float bv[CT];
#pragma unroll
  for (int cc = 0; cc < CT; ++cc) bv[cc] = bias[cc * 16 + cl];
  const int rbase = blk * 64 + (w << 4) + ((l >> 4) << 2);
#pragma unroll
  for (int i = 0; i < 4; ++i) {
    int row = rbase + i;
    if (row < N) {
      float v[CT];
#pragma unroll
      for (int cc = 0; cc < CT; ++cc) {
        v[cc] = acc[cc][i] + bv[cc];
        if (RELU) v[cc] = fmaxf(v[cc], 0.f);
      }
      if (O == 64) {
        uint2 o;
        o.x = bf16pair(v[0], v[1]);
        o.y = bf16pair(v[2], v[3]);
        *(uint2*)(Y + (size_t)row * 64 + cl * 4) = o;
      } else {
        *(unsigned*)(Y + (size_t)row * 32 + cl * 2) = bf16pair(v[0], v[1]);
      }
    }
  }
}

// ---------------------------------------------------------------------------
// Decode: out[e] = dot(z[src[e]], z[dst[e]]) over 32 bf16 features.
__global__ __launch_bounds__(256) void decode_kernel(
    const unsigned* __restrict__ Z, const int* __restrict__ src,
    const int* __restrict__ dst, float* __restrict__ out, int E) {
  int e = blockIdx.x * blockDim.x + threadIdx.x;
  if (e >= E) return;
  const uint4* zs = (const uint4*)(Z + (size_t)src[e] * 16);
  const uint4* zd = (const uint4*)(Z + (size_t)dst[e] * 16);
  uint4 a0 = zs[0], a1 = zs[1], a2 = zs[2], a3 = zs[3];
  uint4 b0 = zd[0], b1 = zd[1], b2 = zd[2], b3 = zd[3];
  out[e] = dot8(a0, b0) + dot8(a1, b1) + dot8(a2, b2) + dot8(a3, b3);
}

// ---------------------------------------------------------------------------
extern "C" void kernel_launch(void* const* d_in, const int* in_sizes, int n_in,
                              void* d_out, int out_size, void* d_ws, size_t ws_size,
                              hipStream_t stream) {
  const float* x     = (const float*)d_in[0];
  const float* W1    = (const float*)d_in[1];
  const float* root1 = (const float*)d_in[2];
  const float* b1    = (const float*)d_in[3];
  const float* W2    = (const float*)d_in[4];
  const float* root2 = (const float*)d_in[5];
  const float* b2    = (const float*)d_in[6];
  const int*   ei    = (const int*)d_in[7];   // [2, E] int32
  const int*   et    = (const int*)d_in[8];   // [E] int32

  const int N = in_sizes[0] / F_IN;           // 100000
  const int E = in_sizes[8];                  // 1000000
  const int nbuck = (N + 511) >> 9;           // 196
  const int nblk64 = nbuck * 8;               // 1568 (64-dst blocks)
  const int* srcp = ei;
  const int* dstp = ei + E;

  // Workspace layout (bytes), peak ~45 MB
  char* ws = (char*)d_ws;
  int*            gcur    = (int*)(ws + 0);              //  800 B [nbuck]
  unsigned*       staging = (unsigned*)(ws + 4096);      //  4.9 MB [200*SCAP]
  int*            startsD = (int*)(ws + 4919296);        //  3.2 MB [nbuck*4097]
  int*            recI    = (int*)(ws + 8131584);        //  4.9 MB [200*SCAP]
  unsigned short* wf1     = (unsigned short*)(ws + 13046784);  // 73.7 KB (9 slots)
  unsigned short* wf2     = (unsigned short*)(ws + 13120512);  // 36.9 KB (9 slots)
  unsigned short* xb      = (unsigned short*)(ws + 13157376);  // 12.8 MB bf16[N*64]
  unsigned short* hmid    = (unsigned short*)(ws + 25957376);  // 12.8 MB bf16[N*64]
  unsigned short* z       = (unsigned short*)(ws + 38757376);  //  6.4 MB bf16[N*32]

  // ---- prep (wf1, wf2, gcur) + x->bf16 + bucketed 2-pass CSR build ----
  prep_kernel<<<28, 256, 0, stream>>>(W1, root1, W2, root2, wf1, wf2, gcur, nbuck);
  cvt_bf16_kernel<<<(N * (F_IN / 8) + 255) / 256, 256, 0, stream>>>(
      x, (unsigned*)xb, N * (F_IN / 8));
  binA_kernel<<<(E + 256 * PA_PE - 1) / (256 * PA_PE), 256, 0, stream>>>(
      srcp, dstp, et, gcur, staging, E);
  binB_kernel<<<nbuck, 256, 0, stream>>>(staging, gcur, recI, startsD);

  // ---- Layer 1: xb -> hmid (bf16, pi64) ----
  ragg_kernel<F_HID, true>
      <<<nblk64, 256, 0, stream>>>(xb, wf1, startsD, recI, b1, hmid, N);

  // ---- Layer 2: hmid -> z (bf16, pi32) ----
  ragg_kernel<F_OUT, false>
      <<<nblk64, 256, 0, stream>>>(hmid, wf2, startsD, recI, b2, z, N);

  // ---- Decode ----
  decode_kernel<<<(E + 255) / 256, 256, 0, stream>>>((const unsigned*)z, srcp, dstp,
                                                     (float*)d_out, E);
}

// Round 14
// 161.248 us; speedup vs baseline: 1.3319x; 1.3319x over previous
//
#include <hip/hip_runtime.h>

// RGCN link predictor (round-8 structure + binA/transform1 fusion):
// MFMA bf16 transforms with direct permuted-layout stores (root fused as 9th
// relation; f32->bf16 conversion fused into layer-1 A-load) + bucketed
// counting-sort CSR build + dst-CSR mean aggregation (pad-8, 8-way unrolled).
// binA (edge binning) and transform1 (write-bound) are independent given
// prep -> fused into ONE dispatch via blockIdx split to overlap their pipes.
//
// Column permutation: H rows store true-col pi(q) = (q%CT)*16 + q/CT at
// short-position q (CT = O/16). hmid inherits pi64 (wprep2 permutes W2's
// k-rows); z inherits pi32; decode dot invariant; bias indexed through pi.
//
// Problem sizes fixed by harness: N=100000, E=1e6 uniform, NREL=8.
#define F_IN 64
#define F_HID 64
#define F_OUT 32
#define NREL 8
#define SCAP 6144    // staging capacity per 512-bucket (edges)
#define RCAP 10240   // rec capacity per bucket (pad-8 slack)
#define MAXBUCK 200
#define PA_PE 16     // edges per thread in binA

typedef __attribute__((ext_vector_type(8))) short bfrag;   // 8 bf16 (A/B frag)
typedef __attribute__((ext_vector_type(4))) float ffrag;   // 4 f32  (C/D frag)

// ---------------------------------------------------------------------------
// bf16 helpers (manual RNE pack)
__device__ inline unsigned short f2bf(float f) {
  unsigned u = __float_as_uint(f);
  unsigned r = (u + 0x7fffu + ((u >> 16) & 1u)) >> 16;
  return (unsigned short)r;
}
__device__ inline unsigned bf16pair(float lo, float hi) {
  return (unsigned)f2bf(lo) | ((unsigned)f2bf(hi) << 16);
}
__device__ inline float bflo(unsigned u) { return __uint_as_float(u << 16); }
__device__ inline float bfhi(unsigned u) { return __uint_as_float(u & 0xffff0000u); }

__device__ inline void acc8(float (&acc)[8], float s, uint4 g) {
  acc[0] += s * bflo(g.x); acc[1] += s * bfhi(g.x);
  acc[2] += s * bflo(g.y); acc[3] += s * bfhi(g.y);
  acc[4] += s * bflo(g.z); acc[5] += s * bfhi(g.z);
  acc[6] += s * bflo(g.w); acc[7] += s * bfhi(g.w);
}
__device__ inline float dot8(uint4 a, uint4 b) {
  return bflo(a.x) * bflo(b.x) + bfhi(a.x) * bfhi(b.x) +
         bflo(a.y) * bflo(b.y) + bfhi(a.y) * bfhi(b.y) +
         bflo(a.z) * bflo(b.z) + bfhi(a.z) * bfhi(b.z) +
         bflo(a.w) * bflo(b.w) + bfhi(a.w) * bfhi(b.w);
}

// ---------------------------------------------------------------------------
// Fused prep: weight fragment swizzle for both layers (+root slots) and
// gcur init. Fragment slot j at lane l holds Wsrc[kperm(k0+j)][c*16+(l&15)],
// k0 = s*32 + (l>>4)*8. PERMK applies pi64 (layer 2's A operand is permuted).
template <int O, bool PERMK>
__device__ inline void wprep_one(int t, const float* __restrict__ W,
                                 const float* __restrict__ root,
                                 unsigned short* __restrict__ Wf) {
  constexpr int CT = O / 16;
  int l = t & 63;
  int s = (t >> 6) & 1;
  int rc = t >> 7;
  int c = rc % CT;
  int r = rc / CT;
  const float* wsrc = (r < NREL) ? W + (size_t)r * 64 * O : root;
  unsigned short* dst = Wf + (size_t)t * 8;
  int col = c * 16 + (l & 15);
  int k0 = s * 32 + ((l >> 4) * 8);
#pragma unroll
  for (int j = 0; j < 8; ++j) {
    int k = k0 + j;
    if (PERMK) k = (k & 3) * 16 + (k >> 2);   // pi64
    dst[j] = f2bf(wsrc[(size_t)k * O + col]);
  }
}

__global__ __launch_bounds__(256) void prep_kernel(
    const float* __restrict__ W1, const float* __restrict__ root1,
    const float* __restrict__ W2, const float* __restrict__ root2,
    unsigned short* __restrict__ wf1, unsigned short* __restrict__ wf2,
    int* __restrict__ gcur, int nbuck) {
  int gid = blockIdx.x * 256 + threadIdx.x;
  const int J1 = (NREL + 1) * (F_HID / 16) * 2 * 64;  // 4608
  const int J2 = (NREL + 1) * (F_OUT / 16) * 2 * 64;  // 2304
  if (gid < J1) {
    wprep_one<F_HID, false>(gid, W1, root1, wf1);
  } else if (gid < J1 + J2) {
    wprep_one<F_OUT, true>(gid - J1, W2, root2, wf2);
  } else if (gid - J1 - J2 < nbuck) {
    int b = gid - J1 - J2;
    gcur[b] = b * SCAP;
  }
}

// ---------------------------------------------------------------------------
// binA body: bin edges by 512-dst bucket into per-bucket staging regions.
// Per-block LDS histogram (per-wave copies; atomicAdd returns in-block rank),
// one global atomic per (block,bucket) reserves a contiguous run.
// Pack: src (17b) | rel (3b, bit17) | dstLow9 (bit20).
__device__ void binA_body(
    const int* __restrict__ src, const int* __restrict__ dst,
    const int* __restrict__ et, int* __restrict__ gcur,
    unsigned* __restrict__ staging, int E) {
  __shared__ int hist[MAXBUCK * 4];
  __shared__ int wbase[MAXBUCK * 4];
  const int tid = threadIdx.x;
  const int wave = tid >> 6;
  for (int i = tid; i < MAXBUCK * 4; i += 256) hist[i] = 0;
  __syncthreads();
  const int base = blockIdx.x * (256 * PA_PE);
  int dv[PA_PE], rk[PA_PE];
#pragma unroll
  for (int j = 0; j < PA_PE; ++j) {
    int e = base + j * 256 + tid;
    if (e < E) {
      int d = dst[e];
      dv[j] = d;
      rk[j] = atomicAdd(&hist[(d >> 9) * 4 + wave], 1);
    } else {
      dv[j] = -1;
    }
  }
  __syncthreads();
  for (int b = tid; b < MAXBUCK; b += 256) {
    int h0 = hist[b * 4 + 0], h1 = hist[b * 4 + 1];
    int h2 = hist[b * 4 + 2], h3 = hist[b * 4 + 3];
    int tot = h0 + h1 + h2 + h3;
    int gb = tot ? atomicAdd(&gcur[b], tot) : 0;
    wbase[b * 4 + 0] = gb;
    wbase[b * 4 + 1] = gb + h0;
    wbase[b * 4 + 2] = gb + h0 + h1;
    wbase[b * 4 + 3] = gb + h0 + h1 + h2;
  }
  __syncthreads();
#pragma unroll
  for (int j = 0; j < PA_PE; ++j) {
    if (dv[j] >= 0) {
      int e = base + j * 256 + tid;
      unsigned pk = (unsigned)src[e] | ((unsigned)et[e] << 17) |
                    ((unsigned)(dv[j] & 511) << 20);
      staging[wbase[(dv[j] >> 9) * 4 + wave] + rk[j]] = pk;
    }
  }
}

// ---------------------------------------------------------------------------
// binB: one block per 512-bucket. Per-(node,rel) counts in LDS (-> pinv),
// in-block scan of pad-8 degrees (-> starts/ends), final 8B records
// {idx=r*N+src, pinv} into the bucket's contiguous rec region, pads zeroed.
__global__ __launch_bounds__(256) void binB_kernel(
    const unsigned* __restrict__ staging, const int* __restrict__ gcur,
    int2* __restrict__ rec, int* __restrict__ startsA, int* __restrict__ endsA,
    int N) {
  __shared__ int cnt8[512 * 8];   // counts, then reused as pinv (float bits)
  __shared__ int cur[512];
  __shared__ int tsum[256];
  const int b = blockIdx.x;
  const int tid = threadIdx.x;
  const int n0 = b << 9;
  const int nn = min(512, N - n0);
  const int cnt_b = gcur[b] - b * SCAP;
  const unsigned* st = staging + (size_t)b * SCAP;
  for (int i = tid; i < 512 * 8; i += 256) cnt8[i] = 0;
  __syncthreads();
  for (int i = tid; i < cnt_b; i += 256) {
    unsigned e = st[i];
    atomicAdd(&cnt8[((e >> 20) & 511) * 8 + ((e >> 17) & 7)], 1);
  }
  __syncthreads();
  const int na = 2 * tid, nb = 2 * tid + 1;
  int deg0 = 0, deg1 = 0;
#pragma unroll
  for (int r = 0; r < 8; ++r) {
    deg0 += cnt8[na * 8 + r];
    deg1 += cnt8[nb * 8 + r];
  }
  const int pd0 = (deg0 + 7) & ~7, pd1 = (deg1 + 7) & ~7;
  tsum[tid] = pd0 + pd1;
  __syncthreads();
  for (int off = 1; off < 256; off <<= 1) {
    int v = (tid >= off) ? tsum[tid - off] : 0;
    __syncthreads();
    tsum[tid] += v;
    __syncthreads();
  }
  const int excl = tsum[tid] - (pd0 + pd1);
  const int s0 = b * RCAP + excl;
  const int s1 = s0 + pd0;
  if (na < nn) { startsA[n0 + na] = s0; endsA[n0 + na] = s0 + pd0; cur[na] = s0; }
  if (nb < nn) { startsA[n0 + nb] = s1; endsA[n0 + nb] = s1 + pd1; cur[nb] = s1; }
  __syncthreads();
  for (int i = tid; i < 512 * 8; i += 256) {
    int cc = cnt8[i];
    ((float*)cnt8)[i] = cc > 0 ? 1.0f / (float)cc : 0.0f;
  }
  __syncthreads();
  for (int i = tid; i < cnt_b; i += 256) {
    unsigned e = st[i];
    int s = e & 0x1FFFF;
    int r = (e >> 17) & 7;
    int dl = (e >> 20) & 511;
    int pos = atomicAdd(&cur[dl], 1);
    rec[pos] = make_int2(r * N + s, ((const int*)cnt8)[dl * 8 + r]);
  }
  __syncthreads();
  if (na < nn) for (int p = cur[na]; p < s0 + pd0; ++p) rec[p] = make_int2(0, 0);
  if (nb < nn) for (int p = cur[nb]; p < s1 + pd1; ++p) rec[p] = make_int2(0, 0);
}

// ---------------------------------------------------------------------------
// MFMA transform body: H[r][n][:] = X[n][:] @ W_r for r in [0,9), slot 8 =
// root. A-fragments loaded once (f32 converted in-reg for layer 1), all 9
// relations looped in-block. Direct permuted-layout stores from the MFMA
// C-fragment: lane l stores its CT per-row values contiguously at
// short-position (l&15)*CT of row (l>>4)*4+i -> true-col pi(q)=(q%CT)*16+q/CT.
template <int O, bool F32IN>
__device__ void transform_body(int blk, const void* __restrict__ Xv,
                               const unsigned short* __restrict__ Wf,
                               unsigned short* __restrict__ H, int N) {
  constexpr int CT = O / 16;
  const int w = threadIdx.x >> 6;
  const int l = threadIdx.x & 63;
  const int nb = blk * 64;
  int arow = nb + w * 16 + (l & 15);
  if (arow >= N) arow = N - 1;  // clamp; stores are guarded
  bfrag a0, a1;
  if (F32IN) {
    const float* xf = (const float*)Xv + (size_t)arow * 64 + ((l >> 4) * 8);
    float4 v0 = *(const float4*)(xf);
    float4 v1 = *(const float4*)(xf + 4);
    float4 v2 = *(const float4*)(xf + 32);
    float4 v3 = *(const float4*)(xf + 36);
    a0[0] = (short)f2bf(v0.x); a0[1] = (short)f2bf(v0.y);
    a0[2] = (short)f2bf(v0.z); a0[3] = (short)f2bf(v0.w);
    a0[4] = (short)f2bf(v1.x); a0[5] = (short)f2bf(v1.y);
    a0[6] = (short)f2bf(v1.z); a0[7] = (short)f2bf(v1.w);
    a1[0] = (short)f2bf(v2.x); a1[1] = (short)f2bf(v2.y);
    a1[2] = (short)f2bf(v2.z); a1[3] = (short)f2bf(v2.w);
    a1[4] = (short)f2bf(v3.x); a1[5] = (short)f2bf(v3.y);
    a1[6] = (short)f2bf(v3.z); a1[7] = (short)f2bf(v3.w);
  } else {
    const unsigned short* xp = (const unsigned short*)Xv + (size_t)arow * 64 + ((l >> 4) * 8);
    a0 = *(const bfrag*)(xp);
    a1 = *(const bfrag*)(xp + 32);
  }
  const int rbase = nb + w * 16 + ((l >> 4) << 2);  // rows rbase..rbase+3
  for (int r = 0; r < NREL + 1; ++r) {
    const unsigned short* wb = Wf + ((size_t)r * CT * 2 * 64 + l) * 8;
    ffrag acc[CT];
#pragma unroll
    for (int c = 0; c < CT; ++c) {
      bfrag b0 = *(const bfrag*)(wb + (size_t)(c * 2 + 0) * 512);
      bfrag b1 = *(const bfrag*)(wb + (size_t)(c * 2 + 1) * 512);
      ffrag z = {0.f, 0.f, 0.f, 0.f};
      acc[c] = __builtin_amdgcn_mfma_f32_16x16x32_bf16(a0, b0, z, 0, 0, 0);
      acc[c] = __builtin_amdgcn_mfma_f32_16x16x32_bf16(a1, b1, acc[c], 0, 0, 0);
    }
#pragma unroll
    for (int i = 0; i < 4; ++i) {
      int row = rbase + i;
      if (row < N) {
        if (O == 64) {
          uint2 v;
          v.x = bf16pair(acc[0][i], acc[1][i]);
          v.y = bf16pair(acc[2][i], acc[3][i]);
          *(uint2*)(H + ((size_t)r * N + row) * 64 + (l & 15) * 4) = v;
        } else {
          *(unsigned*)(H + ((size_t)r * N + row) * 32 + (l & 15) * 2) =
              bf16pair(acc[0][i], acc[1][i]);
        }
      }
    }
  }
}

// Fused dispatch: blocks [0, nbinA) run binA; the rest run transform layer 1.
// Both depend only on prep and write disjoint buffers -> safe to co-schedule.
__global__ __launch_bounds__(256) void binA_t1_kernel(
    const int* __restrict__ src, const int* __restrict__ dst,
    const int* __restrict__ et, int* __restrict__ gcur,
    unsigned* __restrict__ staging, int E, int nbinA,
    const float* __restrict__ x, const unsigned short* __restrict__ wf1,
    unsigned short* __restrict__ h, int N) {
  if ((int)blockIdx.x < nbinA) {
    binA_body(src, dst, et, gcur, staging, E);
  } else {
    transform_body<F_HID, true>((int)blockIdx.x - nbinA, x, wf1, h, N);
  }
}

__global__ __launch_bounds__(256) void transform2_kernel(
    const unsigned short* __restrict__ Xb, const unsigned short* __restrict__ Wf,
    unsigned short* __restrict__ H, int N) {
  transform_body<F_OUT, false>((int)blockIdx.x, Xb, Wf, H, N);
}

// ---------------------------------------------------------------------------
// CSR aggregation: Y[n] = (relu?)( H[8N+n] + bias + sum_p pinv[p]*H[idx[p]] )
// pi-permuted columns; bias indexed through pi. Edge lists padded to
// multiples of 8 with {idx=0, pinv=0} entries. 8 gathers in flight.
template <int O, bool RELU>
__global__ __launch_bounds__(256) void csr_agg_kernel(
    const unsigned* __restrict__ H, const int* __restrict__ startsA,
    const int* __restrict__ endsA, const int2* __restrict__ rec,
    const float* __restrict__ bias, unsigned* __restrict__ Y, int N) {
  constexpr int C = O / 8;       // threads per node, 8 outputs each
  constexpr int NPB = 256 / C;
  constexpr int HROW = O / 2;    // uints per H row
  constexpr int CT = O / 16;
  int t = threadIdx.x;
  int n = blockIdx.x * NPB + t / C;
  int c = t % C;
  if (n >= N) return;
  float acc[8];
  uint4 rr = *(const uint4*)(H + ((size_t)(NREL * N) + n) * HROW + c * 4);
#pragma unroll
  for (int j = 0; j < 8; ++j) {
    int q = c * 8 + j;
    acc[j] = bias[(q % CT) * 16 + q / CT];   // pi(q)
  }
  acc[0] += bflo(rr.x); acc[1] += bfhi(rr.x);
  acc[2] += bflo(rr.y); acc[3] += bfhi(rr.y);
  acc[4] += bflo(rr.z); acc[5] += bfhi(rr.z);
  acc[6] += bflo(rr.w); acc[7] += bfhi(rr.w);
  int p = startsA[n];
  int end = endsA[n];
  for (; p < end; p += 8) {
    int4 e01 = *(const int4*)(rec + p);
    int4 e23 = *(const int4*)(rec + p + 2);
    int4 e45 = *(const int4*)(rec + p + 4);
    int4 e67 = *(const int4*)(rec + p + 6);
    uint4 g0 = *(const uint4*)(H + (size_t)e01.x * HROW + c * 4);
    uint4 g1 = *(const uint4*)(H + (size_t)e01.z * HROW + c * 4);
    uint4 g2 = *(const uint4*)(H + (size_t)e23.x * HROW + c * 4);
    uint4 g3 = *(const uint4*)(H + (size_t)e23.z * HROW + c * 4);
    uint4 g4 = *(const uint4*)(H + (size_t)e45.x * HROW + c * 4);
    uint4 g5 = *(const uint4*)(H + (size_t)e45.z * HROW + c * 4);
    uint4 g6 = *(const uint4*)(H + (size_t)e67.x * HROW + c * 4);
    uint4 g7 = *(const uint4*)(H + (size_t)e67.z * HROW + c * 4);
    acc8(acc, __int_as_float(e01.y), g0);
    acc8(acc, __int_as_float(e01.w), g1);
    acc8(acc, __int_as_float(e23.y), g2);
    acc8(acc, __int_as_float(e23.w), g3);
    acc8(acc, __int_as_float(e45.y), g4);
    acc8(acc, __int_as_float(e45.w), g5);
    acc8(acc, __int_as_float(e67.y), g6);
    acc8(acc, __int_as_float(e67.w), g7);
  }
  if (RELU) {
#pragma unroll
    for (int j = 0; j < 8; ++j) acc[j] = fmaxf(acc[j], 0.f);
  }
  uint4 o;
  o.x = bf16pair(acc[0], acc[1]);
  o.y = bf16pair(acc[2], acc[3]);
  o.z = bf16pair(acc[4], acc[5]);
  o.w = bf16pair(acc[6], acc[7]);
  *(uint4*)(Y + (size_t)n * HROW + c * 4) = o;
}

// ---------------------------------------------------------------------------
// Decode: out[e] = dot(z[src[e]], z[dst[e]]) over 32 bf16 features.
// z is pi32-permuted on both operands -> dot invariant.
__global__ __launch_bounds__(256) void decode_kernel(
    const unsigned* __restrict__ Z, const int* __restrict__ src,
    const int* __restrict__ dst, float* __restrict__ out, int E) {
  int e = blockIdx.x * blockDim.x + threadIdx.x;
  if (e >= E) return;
  const uint4* zs = (const uint4*)(Z + (size_t)src[e] * 16);
  const uint4* zd = (const uint4*)(Z + (size_t)dst[e] * 16);
  uint4 a0 = zs[0], a1 = zs[1], a2 = zs[2], a3 = zs[3];
  uint4 b0 = zd[0], b1 = zd[1], b2 = zd[2], b3 = zd[3];
  out[e] = dot8(a0, b0) + dot8(a1, b1) + dot8(a2, b2) + dot8(a3, b3);
}

// ---------------------------------------------------------------------------
extern "C" void kernel_launch(void* const* d_in, const int* in_sizes, int n_in,
                              void* d_out, int out_size, void* d_ws, size_t ws_size,
                              hipStream_t stream) {
  const float* x     = (const float*)d_in[0];
  const float* W1    = (const float*)d_in[1];
  const float* root1 = (const float*)d_in[2];
  const float* b1    = (const float*)d_in[3];
  const float* W2    = (const float*)d_in[4];
  const float* root2 = (const float*)d_in[5];
  const float* b2    = (const float*)d_in[6];
  const int*   ei    = (const int*)d_in[7];   // [2, E] int32
  const int*   et    = (const int*)d_in[8];   // [E] int32

  const int N = in_sizes[0] / F_IN;           // 100000
  const int E = in_sizes[8];                  // 1000000
  const int nbuck = (N + 511) >> 9;           // 196
  const int nbinA = (E + 256 * PA_PE - 1) / (256 * PA_PE);  // 245
  const int nT1 = (N + 63) / 64;              // 1563
  const int* srcp = ei;
  const int* dstp = ei + E;

  // Workspace layout (bytes), peak ~156 MB (233.6 MB proven available)
  char* ws = (char*)d_ws;
  int*            gcur    = (int*)(ws + 0);             //  800 B [nbuck]
  unsigned*       staging = (unsigned*)(ws + 4096);     //  4.9 MB [200*SCAP]
  int*            startsA = (int*)(ws + 4919296);       //  0.4 MB [N]
  int*            endsA   = (int*)(ws + 5319296);       //  0.4 MB [N]
  int2*           rec     = (int2*)(ws + 5719296);      // 16.1 MB [nbuck*RCAP]
  unsigned short* wf1     = (unsigned short*)(ws + 21775616);  // 73.7 KB (9 slots)
  unsigned short* wf2     = (unsigned short*)(ws + 21849344);  // 36.9 KB (9 slots)
  unsigned short* h       = (unsigned short*)(ws + 21886208);  // 115.2 MB bf16[9N*64]
  unsigned short* hmid    = (unsigned short*)(ws + 137086208); // 12.8 MB bf16[N*64]
  unsigned short* z       = (unsigned short*)(ws + 149886208); //  6.4 MB bf16[N*32]

  // ---- prep (wf1, wf2, gcur) ----
  prep_kernel<<<28, 256, 0, stream>>>(W1, root1, W2, root2, wf1, wf2, gcur, nbuck);

  // ---- fused: binA (edge binning) || transform layer 1 (x -> h) ----
  binA_t1_kernel<<<nbinA + nT1, 256, 0, stream>>>(
      srcp, dstp, et, gcur, staging, E, nbinA, x, wf1, h, N);

  // ---- binB: per-bucket CSR finalize (counts -> pinv, pad-8 lists) ----
  binB_kernel<<<nbuck, 256, 0, stream>>>(staging, gcur, rec, startsA, endsA, N);

  // ---- Layer 1 aggregation: h -> hmid (bf16, pi64) ----
  csr_agg_kernel<F_HID, true>
      <<<(N + 31) / 32, 256, 0, stream>>>((const unsigned*)h, startsA, endsA, rec,
                                          b1, (unsigned*)hmid, N);

  // ---- Layer 2: hmid -> h (bf16, pi32 tiles), then aggregate -> z ----
  transform2_kernel<<<(N + 63) / 64, 256, 0, stream>>>(hmid, wf2, h, N);
  csr_agg_kernel<F_OUT, false>
      <<<(N + 63) / 64, 256, 0, stream>>>((const unsigned*)h, startsA, endsA, rec,
                                          b2, (unsigned*)z, N);

  // ---- Decode ----
  decode_kernel<<<(E + 255) / 256, 256, 0, stream>>>((const unsigned*)z, srcp, dstp,
                                                     (float*)d_out, E);
}

// Round 15
// 155.620 us; speedup vs baseline: 1.3801x; 1.0362x over previous
//
#include <hip/hip_runtime.h>

// RGCN link predictor (round-14 structure, re-cut overlap):
//   prep -> binA -> [binB || transform1] -> csr_agg1 -> transform2 ->
//   csr_agg2 -> decode
// binB (LDS-atomic CSR finalize, depends on binA) is fused with transform1
// (store-stream MFMA, depends only on prep) -- resource-disjoint pipes, the
// short kernel hides under the long one.
//
// MFMA bf16 transforms with direct permuted-layout stores (root fused as 9th
// relation; f32->bf16 conversion fused into layer-1 A-load) + bucketed
// counting-sort CSR build + dst-CSR mean aggregation (pad-8, 8-way unrolled).
// Column permutation: H rows store true-col pi(q) = (q%CT)*16 + q/CT at
// short-position q (CT = O/16). hmid inherits pi64 (wprep2 permutes W2's
// k-rows); z inherits pi32; decode dot invariant; bias indexed through pi.
//
// Problem sizes fixed by harness: N=100000, E=1e6 uniform, NREL=8.
#define F_IN 64
#define F_HID 64
#define F_OUT 32
#define NREL 8
#define SCAP 6144    // staging capacity per 512-bucket (edges)
#define RCAP 10240   // rec capacity per bucket (pad-8 slack)
#define MAXBUCK 200
#define PA_PE 16     // edges per thread in binA

typedef __attribute__((ext_vector_type(8))) short bfrag;   // 8 bf16 (A/B frag)
typedef __attribute__((ext_vector_type(4))) float ffrag;   // 4 f32  (C/D frag)

// ---------------------------------------------------------------------------
// bf16 helpers (manual RNE pack)
__device__ inline unsigned short f2bf(float f) {
  unsigned u = __float_as_uint(f);
  unsigned r = (u + 0x7fffu + ((u >> 16) & 1u)) >> 16;
  return (unsigned short)r;
}
__device__ inline unsigned bf16pair(float lo, float hi) {
  return (unsigned)f2bf(lo) | ((unsigned)f2bf(hi) << 16);
}
__device__ inline float bflo(unsigned u) { return __uint_as_float(u << 16); }
__device__ inline float bfhi(unsigned u) { return __uint_as_float(u & 0xffff0000u); }

__device__ inline void acc8(float (&acc)[8], float s, uint4 g) {
  acc[0] += s * bflo(g.x); acc[1] += s * bfhi(g.x);
  acc[2] += s * bflo(g.y); acc[3] += s * bfhi(g.y);
  acc[4] += s * bflo(g.z); acc[5] += s * bfhi(g.z);
  acc[6] += s * bflo(g.w); acc[7] += s * bfhi(g.w);
}
__device__ inline float dot8(uint4 a, uint4 b) {
  return bflo(a.x) * bflo(b.x) + bfhi(a.x) * bfhi(b.x) +
         bflo(a.y) * bflo(b.y) + bfhi(a.y) * bfhi(b.y) +
         bflo(a.z) * bflo(b.z) + bfhi(a.z) * bfhi(b.z) +
         bflo(a.w) * bflo(b.w) + bfhi(a.w) * bfhi(b.w);
}

// ---------------------------------------------------------------------------
// Fused prep: weight fragment swizzle for both layers (+root slots) and
// gcur init. Fragment slot j at lane l holds Wsrc[kperm(k0+j)][c*16+(l&15)],
// k0 = s*32 + (l>>4)*8. PERMK applies pi64 (layer 2's A operand is permuted).
template <int O, bool PERMK>
__device__ inline void wprep_one(int t, const float* __restrict__ W,
                                 const float* __restrict__ root,
                                 unsigned short* __restrict__ Wf) {
  constexpr int CT = O / 16;
  int l = t & 63;
  int s = (t >> 6) & 1;
  int rc = t >> 7;
  int c = rc % CT;
  int r = rc / CT;
  const float* wsrc = (r < NREL) ? W + (size_t)r * 64 * O : root;
  unsigned short* dst = Wf + (size_t)t * 8;
  int col = c * 16 + (l & 15);
  int k0 = s * 32 + ((l >> 4) * 8);
#pragma unroll
  for (int j = 0; j < 8; ++j) {
    int k = k0 + j;
    if (PERMK) k = (k & 3) * 16 + (k >> 2);   // pi64
    dst[j] = f2bf(wsrc[(size_t)k * O + col]);
  }
}

__global__ __launch_bounds__(256) void prep_kernel(
    const float* __restrict__ W1, const float* __restrict__ root1,
    const float* __restrict__ W2, const float* __restrict__ root2,
    unsigned short* __restrict__ wf1, unsigned short* __restrict__ wf2,
    int* __restrict__ gcur, int nbuck) {
  int gid = blockIdx.x * 256 + threadIdx.x;
  const int J1 = (NREL + 1) * (F_HID / 16) * 2 * 64;  // 4608
  const int J2 = (NREL + 1) * (F_OUT / 16) * 2 * 64;  // 2304
  if (gid < J1) {
    wprep_one<F_HID, false>(gid, W1, root1, wf1);
  } else if (gid < J1 + J2) {
    wprep_one<F_OUT, true>(gid - J1, W2, root2, wf2);
  } else if (gid - J1 - J2 < nbuck) {
    int b = gid - J1 - J2;
    gcur[b] = b * SCAP;
  }
}

// ---------------------------------------------------------------------------
// binA: bin edges by 512-dst bucket into per-bucket staging regions.
// Per-block LDS histogram (per-wave copies; atomicAdd returns in-block rank),
// one global atomic per (block,bucket) reserves a contiguous run.
// Pack: src (17b) | rel (3b, bit17) | dstLow9 (bit20).
__global__ __launch_bounds__(256) void binA_kernel(
    const int* __restrict__ src, const int* __restrict__ dst,
    const int* __restrict__ et, int* __restrict__ gcur,
    unsigned* __restrict__ staging, int E) {
  __shared__ int hist[MAXBUCK * 4];
  __shared__ int wbase[MAXBUCK * 4];
  const int tid = threadIdx.x;
  const int wave = tid >> 6;
  for (int i = tid; i < MAXBUCK * 4; i += 256) hist[i] = 0;
  __syncthreads();
  const int base = blockIdx.x * (256 * PA_PE);
  int dv[PA_PE], rk[PA_PE];
#pragma unroll
  for (int j = 0; j < PA_PE; ++j) {
    int e = base + j * 256 + tid;
    if (e < E) {
      int d = dst[e];
      dv[j] = d;
      rk[j] = atomicAdd(&hist[(d >> 9) * 4 + wave], 1);
    } else {
      dv[j] = -1;
    }
  }
  __syncthreads();
  for (int b = tid; b < MAXBUCK; b += 256) {
    int h0 = hist[b * 4 + 0], h1 = hist[b * 4 + 1];
    int h2 = hist[b * 4 + 2], h3 = hist[b * 4 + 3];
    int tot = h0 + h1 + h2 + h3;
    int gb = tot ? atomicAdd(&gcur[b], tot) : 0;
    wbase[b * 4 + 0] = gb;
    wbase[b * 4 + 1] = gb + h0;
    wbase[b * 4 + 2] = gb + h0 + h1;
    wbase[b * 4 + 3] = gb + h0 + h1 + h2;
  }
  __syncthreads();
#pragma unroll
  for (int j = 0; j < PA_PE; ++j) {
    if (dv[j] >= 0) {
      int e = base + j * 256 + tid;
      unsigned pk = (unsigned)src[e] | ((unsigned)et[e] << 17) |
                    ((unsigned)(dv[j] & 511) << 20);
      staging[wbase[(dv[j] >> 9) * 4 + wave] + rk[j]] = pk;
    }
  }
}

// ---------------------------------------------------------------------------
// binB body: one block per 512-bucket. Per-(node,rel) counts in LDS
// (-> pinv), in-block scan of pad-8 degrees (-> starts/ends), final 8B
// records {idx=r*N+src, pinv} into the contiguous rec region, pads zeroed.
__device__ void binB_body(
    int b, const unsigned* __restrict__ staging, const int* __restrict__ gcur,
    int2* __restrict__ rec, int* __restrict__ startsA, int* __restrict__ endsA,
    int N) {
  __shared__ int cnt8[512 * 8];   // counts, then reused as pinv (float bits)
  __shared__ int cur[512];
  __shared__ int tsum[256];
  const int tid = threadIdx.x;
  const int n0 = b << 9;
  const int nn = min(512, N - n0);
  const int cnt_b = gcur[b] - b * SCAP;
  const unsigned* st = staging + (size_t)b * SCAP;
  for (int i = tid; i < 512 * 8; i += 256) cnt8[i] = 0;
  __syncthreads();
  for (int i = tid; i < cnt_b; i += 256) {
    unsigned e = st[i];
    atomicAdd(&cnt8[((e >> 20) & 511) * 8 + ((e >> 17) & 7)], 1);
  }
  __syncthreads();
  const int na = 2 * tid, nb = 2 * tid + 1;
  int deg0 = 0, deg1 = 0;
#pragma unroll
  for (int r = 0; r < 8; ++r) {
    deg0 += cnt8[na * 8 + r];
    deg1 += cnt8[nb * 8 + r];
  }
  const int pd0 = (deg0 + 7) & ~7, pd1 = (deg1 + 7) & ~7;
  tsum[tid] = pd0 + pd1;
  __syncthreads();
  for (int off = 1; off < 256; off <<= 1) {
    int v = (tid >= off) ? tsum[tid - off] : 0;
    __syncthreads();
    tsum[tid] += v;
    __syncthreads();
  }
  const int excl = tsum[tid] - (pd0 + pd1);
  const int s0 = b * RCAP + excl;
  const int s1 = s0 + pd0;
  if (na < nn) { startsA[n0 + na] = s0; endsA[n0 + na] = s0 + pd0; cur[na] = s0; }
  if (nb < nn) { startsA[n0 + nb] = s1; endsA[n0 + nb] = s1 + pd1; cur[nb] = s1; }
  __syncthreads();
  for (int i = tid; i < 512 * 8; i += 256) {
    int cc = cnt8[i];
    ((float*)cnt8)[i] = cc > 0 ? 1.0f / (float)cc : 0.0f;
  }
  __syncthreads();
  for (int i = tid; i < cnt_b; i += 256) {
    unsigned e = st[i];
    int s = e & 0x1FFFF;
    int r = (e >> 17) & 7;
    int dl = (e >> 20) & 511;
    int pos = atomicAdd(&cur[dl], 1);
    rec[pos] = make_int2(r * N + s, ((const int*)cnt8)[dl * 8 + r]);
  }
  __syncthreads();
  if (na < nn) for (int p = cur[na]; p < s0 + pd0; ++p) rec[p] = make_int2(0, 0);
  if (nb < nn) for (int p = cur[nb]; p < s1 + pd1; ++p) rec[p] = make_int2(0, 0);
}

// ---------------------------------------------------------------------------
// MFMA transform body: H[r][n][:] = X[n][:] @ W_r for r in [0,9), slot 8 =
// root. A-fragments loaded once (f32 converted in-reg for layer 1), all 9
// relations looped in-block. Direct permuted-layout stores from the MFMA
// C-fragment: lane l stores its CT per-row values contiguously at
// short-position (l&15)*CT of row (l>>4)*4+i -> true-col pi(q)=(q%CT)*16+q/CT.
template <int O, bool F32IN>
__device__ void transform_body(int blk, const void* __restrict__ Xv,
                               const unsigned short* __restrict__ Wf,
                               unsigned short* __restrict__ H, int N) {
  constexpr int CT = O / 16;
  const int w = threadIdx.x >> 6;
  const int l = threadIdx.x & 63;
  const int nb = blk * 64;
  int arow = nb + w * 16 + (l & 15);
  if (arow >= N) arow = N - 1;  // clamp; stores are guarded
  bfrag a0, a1;
  if (F32IN) {
    const float* xf = (const float*)Xv + (size_t)arow * 64 + ((l >> 4) * 8);
    float4 v0 = *(const float4*)(xf);
    float4 v1 = *(const float4*)(xf + 4);
    float4 v2 = *(const float4*)(xf + 32);
    float4 v3 = *(const float4*)(xf + 36);
    a0[0] = (short)f2bf(v0.x); a0[1] = (short)f2bf(v0.y);
    a0[2] = (short)f2bf(v0.z); a0[3] = (short)f2bf(v0.w);
    a0[4] = (short)f2bf(v1.x); a0[5] = (short)f2bf(v1.y);
    a0[6] = (short)f2bf(v1.z); a0[7] = (short)f2bf(v1.w);
    a1[0] = (short)f2bf(v2.x); a1[1] = (short)f2bf(v2.y);
    a1[2] = (short)f2bf(v2.z); a1[3] = (short)f2bf(v2.w);
    a1[4] = (short)f2bf(v3.x); a1[5] = (short)f2bf(v3.y);
    a1[6] = (short)f2bf(v3.z); a1[7] = (short)f2bf(v3.w);
  } else {
    const unsigned short* xp = (const unsigned short*)Xv + (size_t)arow * 64 + ((l >> 4) * 8);
    a0 = *(const bfrag*)(xp);
    a1 = *(const bfrag*)(xp + 32);
  }
  const int rbase = nb + w * 16 + ((l >> 4) << 2);  // rows rbase..rbase+3
  for (int r = 0; r < NREL + 1; ++r) {
    const unsigned short* wb = Wf + ((size_t)r * CT * 2 * 64 + l) * 8;
    ffrag acc[CT];
#pragma unroll
    for (int c = 0; c < CT; ++c) {
      bfrag b0 = *(const bfrag*)(wb + (size_t)(c * 2 + 0) * 512);
      bfrag b1 = *(const bfrag*)(wb + (size_t)(c * 2 + 1) * 512);
      ffrag z = {0.f, 0.f, 0.f, 0.f};
      acc[c] = __builtin_amdgcn_mfma_f32_16x16x32_bf16(a0, b0, z, 0, 0, 0);
      acc[c] = __builtin_amdgcn_mfma_f32_16x16x32_bf16(a1, b1, acc[c], 0, 0, 0);
    }
#pragma unroll
    for (int i = 0; i < 4; ++i) {
      int row = rbase + i;
      if (row < N) {
        if (O == 64) {
          uint2 v;
          v.x = bf16pair(acc[0][i], acc[1][i]);
          v.y = bf16pair(acc[2][i], acc[3][i]);
          *(uint2*)(H + ((size_t)r * N + row) * 64 + (l & 15) * 4) = v;
        } else {
          *(unsigned*)(H + ((size_t)r * N + row) * 32 + (l & 15) * 2) =
              bf16pair(acc[0][i], acc[1][i]);
        }
      }
    }
  }
}

// Fused dispatch: blocks [0, nbuck) run binB (depends on binA); the rest run
// transform layer 1 (depends only on prep). Disjoint outputs; binB's
// LDS-atomic work hides under transform1's store stream.
__global__ __launch_bounds__(256) void binB_t1_kernel(
    const unsigned* __restrict__ staging, const int* __restrict__ gcur,
    int2* __restrict__ rec, int* __restrict__ startsA, int* __restrict__ endsA,
    int nbuck, const float* __restrict__ x,
    const unsigned short* __restrict__ wf1, unsigned short* __restrict__ h,
    int N) {
  if ((int)blockIdx.x < nbuck) {
    binB_body((int)blockIdx.x, staging, gcur, rec, startsA, endsA, N);
  } else {
    transform_body<F_HID, true>((int)blockIdx.x - nbuck, x, wf1, h, N);
  }
}

__global__ __launch_bounds__(256) void transform2_kernel(
    const unsigned short* __restrict__ Xb, const unsigned short* __restrict__ Wf,
    unsigned short* __restrict__ H, int N) {
  transform_body<F_OUT, false>((int)blockIdx.x, Xb, Wf, H, N);
}

// ---------------------------------------------------------------------------
// CSR aggregation: Y[n] = (relu?)( H[8N+n] + bias + sum_p pinv[p]*H[idx[p]] )
// pi-permuted columns; bias indexed through pi. Edge lists padded to
// multiples of 8 with {idx=0, pinv=0} entries. 8 gathers in flight.
template <int O, bool RELU>
__global__ __launch_bounds__(256) void csr_agg_kernel(
    const unsigned* __restrict__ H, const int* __restrict__ startsA,
    const int* __restrict__ endsA, const int2* __restrict__ rec,
    const float* __restrict__ bias, unsigned* __restrict__ Y, int N) {
  constexpr int C = O / 8;       // threads per node, 8 outputs each
  constexpr int NPB = 256 / C;
  constexpr int HROW = O / 2;    // uints per H row
  constexpr int CT = O / 16;
  int t = threadIdx.x;
  int n = blockIdx.x * NPB + t / C;
  int c = t % C;
  if (n >= N) return;
  float acc[8];
  uint4 rr = *(const uint4*)(H + ((size_t)(NREL * N) + n) * HROW + c * 4);
#pragma unroll
  for (int j = 0; j < 8; ++j) {
    int q = c * 8 + j;
    acc[j] = bias[(q % CT) * 16 + q / CT];   // pi(q)
  }
  acc[0] += bflo(rr.x); acc[1] += bfhi(rr.x);
  acc[2] += bflo(rr.y); acc[3] += bfhi(rr.y);
  acc[4] += bflo(rr.z); acc[5] += bfhi(rr.z);
  acc[6] += bflo(rr.w); acc[7] += bfhi(rr.w);
  int p = startsA[n];
  int end = endsA[n];
  for (; p < end; p += 8) {
    int4 e01 = *(const int4*)(rec + p);
    int4 e23 = *(const int4*)(rec + p + 2);
    int4 e45 = *(const int4*)(rec + p + 4);
    int4 e67 = *(const int4*)(rec + p + 6);
    uint4 g0 = *(const uint4*)(H + (size_t)e01.x * HROW + c * 4);
    uint4 g1 = *(const uint4*)(H + (size_t)e01.z * HROW + c * 4);
    uint4 g2 = *(const uint4*)(H + (size_t)e23.x * HROW + c * 4);
    uint4 g3 = *(const uint4*)(H + (size_t)e23.z * HROW + c * 4);
    uint4 g4 = *(const uint4*)(H + (size_t)e45.x * HROW + c * 4);
    uint4 g5 = *(const uint4*)(H + (size_t)e45.z * HROW + c * 4);
    uint4 g6 = *(const uint4*)(H + (size_t)e67.x * HROW + c * 4);
    uint4 g7 = *(const uint4*)(H + (size_t)e67.z * HROW + c * 4);
    acc8(acc, __int_as_float(e01.y), g0);
    acc8(acc, __int_as_float(e01.w), g1);
    acc8(acc, __int_as_float(e23.y), g2);
    acc8(acc, __int_as_float(e23.w), g3);
    acc8(acc, __int_as_float(e45.y), g4);
    acc8(acc, __int_as_float(e45.w), g5);
    acc8(acc, __int_as_float(e67.y), g6);
    acc8(acc, __int_as_float(e67.w), g7);
  }
  if (RELU) {
#pragma unroll
    for (int j = 0; j < 8; ++j) acc[j] = fmaxf(acc[j], 0.f);
  }
  uint4 o;
  o.x = bf16pair(acc[0], acc[1]);
  o.y = bf16pair(acc[2], acc[3]);
  o.z = bf16pair(acc[4], acc[5]);
  o.w = bf16pair(acc[6], acc[7]);
  *(uint4*)(Y + (size_t)n * HROW + c * 4) = o;
}

// ---------------------------------------------------------------------------
// Decode: out[e] = dot(z[src[e]], z[dst[e]]) over 32 bf16 features.
// z is pi32-permuted on both operands -> dot invariant.
__global__ __launch_bounds__(256) void decode_kernel(
    const unsigned* __restrict__ Z, const int* __restrict__ src,
    const int* __restrict__ dst, float* __restrict__ out, int E) {
  int e = blockIdx.x * blockDim.x + threadIdx.x;
  if (e >= E) return;
  const uint4* zs = (const uint4*)(Z + (size_t)src[e] * 16);
  const uint4* zd = (const uint4*)(Z + (size_t)dst[e] * 16);
  uint4 a0 = zs[0], a1 = zs[1], a2 = zs[2], a3 = zs[3];
  uint4 b0 = zd[0], b1 = zd[1], b2 = zd[2], b3 = zd[3];
  out[e] = dot8(a0, b0) + dot8(a1, b1) + dot8(a2, b2) + dot8(a3, b3);
}

// ---------------------------------------------------------------------------
extern "C" void kernel_launch(void* const* d_in, const int* in_sizes, int n_in,
                              void* d_out, int out_size, void* d_ws, size_t ws_size,
                              hipStream_t stream) {
  const float* x     = (const float*)d_in[0];
  const float* W1    = (const float*)d_in[1];
  const float* root1 = (const float*)d_in[2];
  const float* b1    = (const float*)d_in[3];
  const float* W2    = (const float*)d_in[4];
  const float* root2 = (const float*)d_in[5];
  const float* b2    = (const float*)d_in[6];
  const int*   ei    = (const int*)d_in[7];   // [2, E] int32
  const int*   et    = (const int*)d_in[8];   // [E] int32

  const int N = in_sizes[0] / F_IN;           // 100000
  const int E = in_sizes[8];                  // 1000000
  const int nbuck = (N + 511) >> 9;           // 196
  const int nbinA = (E + 256 * PA_PE - 1) / (256 * PA_PE);  // 245
  const int nT1 = (N + 63) / 64;              // 1563
  const int* srcp = ei;
  const int* dstp = ei + E;

  // Workspace layout (bytes), peak ~156 MB (233.6 MB proven available)
  char* ws = (char*)d_ws;
  int*            gcur    = (int*)(ws + 0);             //  800 B [nbuck]
  unsigned*       staging = (unsigned*)(ws + 4096);     //  4.9 MB [200*SCAP]
  int*            startsA = (int*)(ws + 4919296);       //  0.4 MB [N]
  int*            endsA   = (int*)(ws + 5319296);       //  0.4 MB [N]
  int2*           rec     = (int2*)(ws + 5719296);      // 16.1 MB [nbuck*RCAP]
  unsigned short* wf1     = (unsigned short*)(ws + 21775616);  // 73.7 KB (9 slots)
  unsigned short* wf2     = (unsigned short*)(ws + 21849344);  // 36.9 KB (9 slots)
  unsigned short* h       = (unsigned short*)(ws + 21886208);  // 115.2 MB bf16[9N*64]
  unsigned short* hmid    = (unsigned short*)(ws + 137086208); // 12.8 MB bf16[N*64]
  unsigned short* z       = (unsigned short*)(ws + 149886208); //  6.4 MB bf16[N*32]

  // ---- prep (wf1, wf2, gcur) ----
  prep_kernel<<<28, 256, 0, stream>>>(W1, root1, W2, root2, wf1, wf2, gcur, nbuck);

  // ---- binA: edge binning into bucket staging ----
  binA_kernel<<<nbinA, 256, 0, stream>>>(srcp, dstp, et, gcur, staging, E);

  // ---- fused: binB (CSR finalize) || transform layer 1 (x -> h) ----
  binB_t1_kernel<<<nbuck + nT1, 256, 0, stream>>>(
      staging, gcur, rec, startsA, endsA, nbuck, x, wf1, h, N);

  // ---- Layer 1 aggregation: h -> hmid (bf16, pi64) ----
  csr_agg_kernel<F_HID, true>
      <<<(N + 31) / 32, 256, 0, stream>>>((const unsigned*)h, startsA, endsA, rec,
                                          b1, (unsigned*)hmid, N);

  // ---- Layer 2: hmid -> h (bf16, pi32 tiles), then aggregate -> z ----
  transform2_kernel<<<(N + 63) / 64, 256, 0, stream>>>(hmid, wf2, h, N);
  csr_agg_kernel<F_OUT, false>
      <<<(N + 63) / 64, 256, 0, stream>>>((const unsigned*)h, startsA, endsA, rec,
                                          b2, (unsigned*)z, N);

  // ---- Decode ----
  decode_kernel<<<(E + 255) / 256, 256, 0, stream>>>((const unsigned*)z, srcp, dstp,
                                                     (float*)d_out, E);
}